// Round 3
// baseline (1371.447 us; speedup 1.0000x reference)
//
#include <hip/hip_runtime.h>

#define EPS 1e-5f

typedef _Float16 half8_t __attribute__((ext_vector_type(8)));
typedef _Float16 half4_t __attribute__((ext_vector_type(4)));
typedef float    float4_t __attribute__((ext_vector_type(4)));

// Fast tanh-form GELU via exp2. Max |err| vs exact erf-GELU ~5e-4.
__device__ __forceinline__ float gelu_f(float v) {
  float u2 = v * v;
  float a  = __builtin_fmaf(u2, -0.10294322f, -2.3022078f);
  float e  = __builtin_amdgcn_exp2f(v * a);
  return v * __builtin_amdgcn_rcpf(1.0f + e);
}

// ---- LDS swizzle for [64][128] fp16 tiles, row stride 128 halfs (256 B) ----
// Row stride 256 B ≡ 0 mod banks, so column-slice reads (16 rows, same col-
// group) and staging stores (rows 4*pg+r, same col) both serialize unless the
// 16-B column-group index is XOR'd with a row hash. Hash (p + p>>2)&15 spans
// all 16 values for BOTH access families: staging rows 4pg+r -> 5pg+r mod 16
// (gcd(5,16)=1), fragment rows mt*16+l16 -> l16+(l16>>2) (13+ distinct).
__device__ __forceinline__ int swz(int p, int c) {
  int g = (p + (p >> 2)) & 15;
  return (((c >> 3) ^ g) << 3) | (c & 7);
}
__device__ __forceinline__ int swz8(int p, int cg) {   // c aligned to 8: c = cg*8
  int g = (p + (p >> 2)) & 15;
  return (cg ^ g) << 3;
}

// DPP-based sum over the 16 lanes of a row (lanes l&15 hold d=0..15).
template<int CTRL>
__device__ __forceinline__ float dpp_add(float v) {
  int j = __builtin_amdgcn_update_dpp(0, __float_as_int(v), CTRL, 0xF, 0xF, true);
  return v + __int_as_float(j);
}
__device__ __forceinline__ float rsum16(float v) {
  v = dpp_add<0xB1>(v);   // quad_perm {1,0,3,2}  : xor 1
  v = dpp_add<0x4E>(v);   // quad_perm {2,3,0,1}  : xor 2
  v = dpp_add<0x124>(v);  // row_ror:4
  v = dpp_add<0x128>(v);  // row_ror:8
  return v;
}

// ---------------- weight conversion (fp32 -> fp16, reordered) ----------------
// kvw rows r in [0,256): h=r>>5, rr=r&31 -> qkv row h*48+16+rr (k then v per head)
//   LN-mean folding: subtract the per-head 16-row mean of the k (or v) block.
// qw  rows r in [0,128): h=r>>4, d=r&15 -> qkv row h*48+d
__global__ __launch_bounds__(256)
void k_wconv(const float* __restrict__ qkvw, const float* __restrict__ o1w,
             const float* __restrict__ o2w, _Float16* __restrict__ kvw,
             _Float16* __restrict__ qw, _Float16* __restrict__ o1h,
             _Float16* __restrict__ o2h) {
  int t = blockIdx.x * 256 + threadIdx.x;        // 0..81919
  if (t < 32768) {
    int r = t >> 7, c = t & 127;
    int h = r >> 5, rr = r & 31;
    int src = h * 48 + 16 + rr;
    int mb  = h * 48 + 16 + (rr & 16);           // base row of this k- or v-block
    float s = 0.0f;
#pragma unroll
    for (int d = 0; d < 16; d++) s += qkvw[(mb + d) * 128 + c];
    kvw[t] = (_Float16)(qkvw[src * 128 + c] - 0.0625f * s);
  } else if (t < 49152) {
    int i = t - 32768;
    int r = i >> 7, c = i & 127;
    int src = (r >> 4) * 48 + (r & 15);
    qw[i] = (_Float16)qkvw[src * 128 + c];
  } else if (t < 65536) {
    int i = t - 49152;
    o1h[i] = (_Float16)o1w[i];
  } else {
    int i = t - 65536;
    o2h[i] = (_Float16)o2w[i];
  }
}

// ---------------- kernel A: k,v GEMM + LayerNorm + kv outer-product partials --
// Grid 2048 = 8 b * 256 cb; each block: 4 chunks of 64 px. Wave w owns heads 2w,2w+1.
// (256,3): unified VGPR budget 512/3=170 >= ~150 used -> NO scratch spill
// ((256,5) = 102-reg budget spilled the AGPR accumulators: +500MB HBM, round 2).
// Ping-pong LDS x-tile: one barrier per chunk; next chunk's global loads are
// issued 4-before/4-after the GEMM so HBM latency hides under MFMA.
__global__ __launch_bounds__(256, 3)
void k_qkv_kv(const float* __restrict__ x, const _Float16* __restrict__ kvw,
              const float* __restrict__ klw, const float* __restrict__ klb,
              const float* __restrict__ vlw, const float* __restrict__ vlb,
              float* __restrict__ partial) {
  __shared__ _Float16 xs[2][8192];               // 2 x 64px x 128ch, swizzled
  const int t = threadIdx.x;
  const int lane = t & 63, w = t >> 6;
  const int quad = lane >> 4, l16 = lane & 15;
  const int b = blockIdx.x >> 8, cb = blockIdx.x & 255;
  const float* xb = x + (long)b * 8388608;       // b*128*65536
  const int cbase = t >> 4, pg = t & 15, p0 = 4 * pg;

  float kw0[2], kb0[2], vw0[2], vb0[2];
#pragma unroll
  for (int hh = 0; hh < 2; hh++) {
    int h = 2 * w + hh;
    kw0[hh] = klw[h * 16 + l16]; kb0[hh] = klb[h * 16 + l16];
    vw0[hh] = vlw[h * 16 + l16]; vb0[hh] = vlb[h * 16 + l16];
  }

  float4_t kvacc[2] = {};                        // kv accumulator, C-layout
  float4 ld[8];

  // prologue: stage chunk 0 into regs
#pragma unroll
  for (int i = 0; i < 8; i++)
    ld[i] = *(const float4*)(xb + ((long)(i * 16 + cbase) << 16) + cb * 256 + p0);

  for (int ch = 0; ch < 4; ch++) {
    _Float16* bs = xs[ch & 1];
    // regs -> LDS (swizzled; ~2-way after same-word merge, was 32-way)
#pragma unroll
    for (int i = 0; i < 8; i++) {
      int c = i * 16 + cbase;
      bs[(p0 + 0) * 128 + swz(p0 + 0, c)] = (_Float16)ld[i].x;
      bs[(p0 + 1) * 128 + swz(p0 + 1, c)] = (_Float16)ld[i].y;
      bs[(p0 + 2) * 128 + swz(p0 + 2, c)] = (_Float16)ld[i].z;
      bs[(p0 + 3) * 128 + swz(p0 + 3, c)] = (_Float16)ld[i].w;
    }
    __syncthreads();                             // single barrier per chunk

    const int n1 = cb * 256 + (ch + 1) * 64;
    if (ch < 3) {                                // prefetch half 1 (16 regs live)
#pragma unroll
      for (int i = 0; i < 4; i++)
        ld[i] = *(const float4*)(xb + ((long)(i * 16 + cbase) << 16) + n1 + p0);
    }

    // C[p][och] = X[p][c] * Wkv[och][c]; wave och slice = [64w, 64w+64)
    float4_t acc[4][4] = {};                     // [m-tile][o-tile]
#pragma unroll
    for (int k = 0; k < 4; k++) {
      half8_t A[4];
#pragma unroll
      for (int mt = 0; mt < 4; mt++) {
        int row = mt * 16 + l16;
        A[mt] = *(const half8_t*)(bs + row * 128 + swz8(row, k * 4 + quad));
      }
#pragma unroll
      for (int ot = 0; ot < 4; ot++) {
        half8_t Bf = *(const half8_t*)(kvw + (w * 64 + ot * 16 + l16) * 128 + k * 32 + quad * 8);
#pragma unroll
        for (int mt = 0; mt < 4; mt++)
          acc[mt][ot] = __builtin_amdgcn_mfma_f32_16x16x32_f16(A[mt], Bf, acc[mt][ot], 0, 0, 0);
      }
    }

    if (ch < 3) {                                // prefetch half 2
#pragma unroll
      for (int i = 4; i < 8; i++)
        ld[i] = *(const float4*)(xb + ((long)(i * 16 + cbase) << 16) + n1 + p0);
    }

    // LN(k), LN(v): mean pre-folded into kvw -> std = sqrt(sum(k'^2)/15),
    // inv = rcp(std + EPS).  Then kv += K^T V via 16x16x16 MFMA.
#pragma unroll
    for (int hh = 0; hh < 2; hh++) {
#pragma unroll
      for (int mt = 0; mt < 4; mt++) {
        half4_t kf, vf;
#pragma unroll
        for (int rr = 0; rr < 4; rr++) {
          float kx = acc[mt][2 * hh + 0][rr];
          float vx = acc[mt][2 * hh + 1][rr];
          float s2k = rsum16(kx * kx);
          float s2v = rsum16(vx * vx);
          float rk = __builtin_amdgcn_rcpf(
              __builtin_fmaf(__builtin_amdgcn_sqrtf(s2k), 0.25819889f, EPS));
          float rv = __builtin_amdgcn_rcpf(
              __builtin_fmaf(__builtin_amdgcn_sqrtf(s2v), 0.25819889f, EPS));
          kf[rr] = (_Float16)((kw0[hh] * rk) * kx + kb0[hh]);
          vf[rr] = (_Float16)((vw0[hh] * rv) * vx + vb0[hh]);
        }
        kvacc[hh] = __builtin_amdgcn_mfma_f32_16x16x16f16(kf, vf, kvacc[hh], 0, 0, 0);
      }
    }
    // no trailing barrier: next chunk writes the OTHER buffer; the top-of-loop
    // barrier orders its readers.
  }

  // write per-block partial kv: [block][h][d][e]
#pragma unroll
  for (int hh = 0; hh < 2; hh++) {
    int h = 2 * w + hh;
#pragma unroll
    for (int rr = 0; rr < 4; rr++) {
      int d = quad * 4 + rr;
      partial[((long)blockIdx.x * 8 + h) * 256 + d * 16 + l16] = kvacc[hh][rr];
    }
  }
}

// ---------------- reducer: sum partials, /N, store transposed kvT[b][h][e][d] --
__global__ __launch_bounds__(256)
void k_reduce(const float* __restrict__ partial, float* __restrict__ kvT) {
  const int bh = blockIdx.x;                     // b*8+h
  const int t = threadIdx.x;                     // d*16+e
  const int b = bh >> 3, h = bh & 7;
  float s = 0.0f;
#pragma unroll 8
  for (int cb = 0; cb < 256; cb++)
    s += partial[((long)(b * 256 + cb) * 8 + h) * 256 + t];
  kvT[(bh << 8) + (t & 15) * 16 + (t >> 4)] = s * (1.0f / 65536.0f);
}

// ---------------- shared GEMM helper: C[p][och], och slice [32w,32w+32) -------
// src is a swizzled [64][128] tile (row stride 128).
__device__ __forceinline__ void gemm_128(const _Float16* src, const _Float16* wgt,
                                         int w, int l16, int quad, float4_t (&acc)[4][2]) {
#pragma unroll
  for (int k = 0; k < 4; k++) {
    half8_t A[4];
#pragma unroll
    for (int mt = 0; mt < 4; mt++) {
      int row = mt * 16 + l16;
      A[mt] = *(const half8_t*)(src + row * 128 + swz8(row, k * 4 + quad));
    }
#pragma unroll
    for (int ot = 0; ot < 2; ot++) {
      half8_t Bf = *(const half8_t*)(wgt + (w * 32 + ot * 16 + l16) * 128 + k * 32 + quad * 8);
#pragma unroll
      for (int mt = 0; mt < 4; mt++)
        acc[mt][ot] = __builtin_amdgcn_mfma_f32_16x16x32_f16(A[mt], Bf, acc[mt][ot], 0, 0, 0);
    }
  }
}

// ---------------- kernel C: q GEMM + q@kv + residual + o1/gelu + o2/gelu ------
// Two swizzled LDS tiles (32 KB): q->ret in place (wave-exclusive logical
// columns; swizzle is a per-row bijection so physical cells stay exclusive),
// y-residual x snapshotted to 32 half regs before u overwrites bufA.
__global__ __launch_bounds__(256, 4)
void k_attn_out(const float* __restrict__ x, const _Float16* __restrict__ qw,
                const _Float16* __restrict__ o1h, const _Float16* __restrict__ o2h,
                const float* __restrict__ kvT, float* __restrict__ out) {
  __shared__ _Float16 bufA[8192];                // x, later u (swizzled)
  __shared__ _Float16 bufB[8192];                // q -> ret (in place), later y
  const int t = threadIdx.x;
  const int lane = t & 63, w = t >> 6;
  const int quad = lane >> 4, l16 = lane & 15;
  const int b = blockIdx.x >> 10;
  const int n0 = (blockIdx.x & 1023) << 6;
  const float* xb = x + (long)b * 8388608;
  const int cbase = t >> 4, pg = t & 15, p0 = 4 * pg;

#pragma unroll
  for (int i = 0; i < 8; i++) {
    int c = i * 16 + cbase;
    float4 v = *(const float4*)(xb + ((long)c << 16) + n0 + p0);
    bufA[(p0 + 0) * 128 + swz(p0 + 0, c)] = (_Float16)v.x;
    bufA[(p0 + 1) * 128 + swz(p0 + 1, c)] = (_Float16)v.y;
    bufA[(p0 + 2) * 128 + swz(p0 + 2, c)] = (_Float16)v.z;
    bufA[(p0 + 3) * 128 + swz(p0 + 3, c)] = (_Float16)v.w;
  }

  // preload kv B-fragments for this wave's 2 heads: B[k=d][n=e] from kvT[b][h][e][d]
  half4_t kvf[2];
#pragma unroll
  for (int hh = 0; hh < 2; hh++) {
    int h = 2 * w + hh;
    float4 kq = *(const float4*)(kvT + ((b * 8 + h) << 8) + l16 * 16 + quad * 4);
    kvf[hh][0] = (_Float16)kq.x; kvf[hh][1] = (_Float16)kq.y;
    kvf[hh][2] = (_Float16)kq.z; kvf[hh][3] = (_Float16)kq.w;
  }
  __syncthreads();

  // q = x @ qw^T  (och slice [32w,32w+32)) -> bufB
  float4_t qa[4][2] = {};
  gemm_128(bufA, qw, w, l16, quad, qa);
#pragma unroll
  for (int mt = 0; mt < 4; mt++)
#pragma unroll
    for (int ot = 0; ot < 2; ot++)
#pragma unroll
      for (int rr = 0; rr < 4; rr++) {
        int p = mt * 16 + quad * 4 + rr, c = w * 32 + ot * 16 + l16;
        bufB[p * 128 + swz(p, c)] = (_Float16)qa[mt][ot][rr];
      }

  // o = q @ kv ; ret = o + x  (in place over q: wave-exclusive logical columns,
  // in-wave lgkmcnt ordering protects read-then-write within the wave)
#pragma unroll
  for (int hh = 0; hh < 2; hh++) {
    int h = 2 * w + hh;
#pragma unroll
    for (int mt = 0; mt < 4; mt++) {
      int row = mt * 16 + l16;
      half4_t qf = *(const half4_t*)(bufB + row * 128 + swz(row, h * 16 + quad * 4));
      float4_t oacc = {};
      oacc = __builtin_amdgcn_mfma_f32_16x16x16f16(qf, kvf[hh], oacc, 0, 0, 0);
#pragma unroll
      for (int rr = 0; rr < 4; rr++) {
        int p = mt * 16 + quad * 4 + rr, c = h * 16 + l16;
        bufB[p * 128 + swz(p, c)] = (_Float16)(oacc[rr] + (float)bufA[p * 128 + swz(p, c)]);
      }
    }
  }

  // snapshot the y-stage residual x values before bufA is overwritten by u
  _Float16 xres[4][2][4];                        // static indexing -> registers
#pragma unroll
  for (int mt = 0; mt < 4; mt++)
#pragma unroll
    for (int ot = 0; ot < 2; ot++)
#pragma unroll
      for (int rr = 0; rr < 4; rr++) {
        int p = mt * 16 + quad * 4 + rr, c = w * 32 + ot * 16 + l16;
        xres[mt][ot][rr] = bufA[p * 128 + swz(p, c)];
      }
  __syncthreads();                               // ret complete + bufA reads done

  // u = gelu(ret @ o1^T) -> bufA
  float4_t ua[4][2] = {};
  gemm_128(bufB, o1h, w, l16, quad, ua);
#pragma unroll
  for (int mt = 0; mt < 4; mt++)
#pragma unroll
    for (int ot = 0; ot < 2; ot++)
#pragma unroll
      for (int rr = 0; rr < 4; rr++) {
        int p = mt * 16 + quad * 4 + rr, c = w * 32 + ot * 16 + l16;
        bufA[p * 128 + swz(p, c)] = (_Float16)gelu_f(ua[mt][ot][rr]);
      }
  __syncthreads();

  // y = gelu(u @ o2^T + x) -> bufB (ret dead: all bufB reads done at barrier)
  float4_t ya[4][2] = {};
  gemm_128(bufA, o2h, w, l16, quad, ya);
#pragma unroll
  for (int mt = 0; mt < 4; mt++)
#pragma unroll
    for (int ot = 0; ot < 2; ot++)
#pragma unroll
      for (int rr = 0; rr < 4; rr++) {
        int p = mt * 16 + quad * 4 + rr, c = w * 32 + ot * 16 + l16;
        bufB[p * 128 + swz(p, c)] = (_Float16)gelu_f(ya[mt][ot][rr] + (float)xres[mt][ot][rr]);
      }
  __syncthreads();

  // coalesced fp32 store via LDS transpose
#pragma unroll
  for (int i = 0; i < 8; i++) {
    int c = i * 16 + cbase;
    float4 o4;
    o4.x = (float)bufB[(p0 + 0) * 128 + swz(p0 + 0, c)];
    o4.y = (float)bufB[(p0 + 1) * 128 + swz(p0 + 1, c)];
    o4.z = (float)bufB[(p0 + 2) * 128 + swz(p0 + 2, c)];
    o4.w = (float)bufB[(p0 + 3) * 128 + swz(p0 + 3, c)];
    *(float4*)(out + ((long)b * 128 + c) * 65536 + n0 + p0) = o4;
  }
}

extern "C" void kernel_launch(void* const* d_in, const int* in_sizes, int n_in,
                              void* d_out, int out_size, void* d_ws, size_t ws_size,
                              hipStream_t stream) {
  const float* x    = (const float*)d_in[0];
  const float* qkvw = (const float*)d_in[1];
  const float* o1w  = (const float*)d_in[2];
  const float* o2w  = (const float*)d_in[3];
  const float* klw  = (const float*)d_in[4];
  const float* klb  = (const float*)d_in[5];
  const float* vlw  = (const float*)d_in[6];
  const float* vlb  = (const float*)d_in[7];
  float* out = (float*)d_out;
  char* ws = (char*)d_ws;
  _Float16* kvw  = (_Float16*)(ws + 0);        // 256x128 fp16   (64 KB)
  _Float16* qw   = (_Float16*)(ws + 65536);    // 128x128 fp16   (32 KB)
  _Float16* o1h  = (_Float16*)(ws + 98304);    // 128x128 fp16   (32 KB)
  _Float16* o2h  = (_Float16*)(ws + 131072);   // 128x128 fp16   (32 KB)
  float* kvT     = (float*)(ws + 163840);      // 8x8x16x16 fp32 (64 KB)
  float* partial = (float*)(ws + 229376);      // 2048x8x256 fp32 (16 MB)

  k_wconv<<<320, 256, 0, stream>>>(qkvw, o1w, o2w, kvw, qw, o1h, o2h);
  k_qkv_kv<<<2048, 256, 0, stream>>>(x, kvw, klw, klb, vlw, vlb, partial);
  k_reduce<<<64, 256, 0, stream>>>(partial, kvT);
  k_attn_out<<<8192, 256, 0, stream>>>(x, qw, o1h, o2h, kvT, out);
}

// Round 4
// 1032.132 us; speedup vs baseline: 1.3288x; 1.3288x over previous
//
#include <hip/hip_runtime.h>

#define EPS 1e-5f

typedef _Float16 half8_t __attribute__((ext_vector_type(8)));
typedef _Float16 half4_t __attribute__((ext_vector_type(4)));
typedef float    float4_t __attribute__((ext_vector_type(4)));

// Fast tanh-form GELU via exp2. Max |err| vs exact erf-GELU ~5e-4.
__device__ __forceinline__ float gelu_f(float v) {
  float u2 = v * v;
  float a  = __builtin_fmaf(u2, -0.10294322f, -2.3022078f);
  float e  = __builtin_amdgcn_exp2f(v * a);
  return v * __builtin_amdgcn_rcpf(1.0f + e);
}

// ---- LDS swizzle for [64][128] fp16 tiles, row stride 128 halfs (256 B) ----
// 16-B column-granule index XOR'd with row hash (p + p>>2)&15; bijective per
// row, spreads both staging stores (rows 4pg+r) and fragment reads (rows
// mt*16+l16) across banks.
__device__ __forceinline__ int swz(int p, int c) {
  int g = (p + (p >> 2)) & 15;
  return (((c >> 3) ^ g) << 3) | (c & 7);
}
__device__ __forceinline__ int swz8(int p, int cg) {   // c aligned to 8: c = cg*8
  int g = (p + (p >> 2)) & 15;
  return (cg ^ g) << 3;
}

// DPP-based sum over the 16 lanes of a row (lanes l&15 hold d=0..15).
template<int CTRL>
__device__ __forceinline__ float dpp_add(float v) {
  int j = __builtin_amdgcn_update_dpp(0, __float_as_int(v), CTRL, 0xF, 0xF, true);
  return v + __int_as_float(j);
}
__device__ __forceinline__ float rsum16(float v) {
  v = dpp_add<0xB1>(v);   // quad_perm {1,0,3,2}  : xor 1
  v = dpp_add<0x4E>(v);   // quad_perm {2,3,0,1}  : xor 2
  v = dpp_add<0x124>(v);  // row_ror:4
  v = dpp_add<0x128>(v);  // row_ror:8
  return v;
}

// ---------------- weight conversion (fp32 -> fp16, reordered) ----------------
// kvw rows r in [0,256): h=r>>5, rr=r&31 -> qkv row h*48+16+rr (k then v per head)
//   LN-mean folding: subtract the per-head 16-row mean of the k (or v) block.
// qw  rows r in [0,128): h=r>>4, d=r&15 -> qkv row h*48+d
__global__ __launch_bounds__(256)
void k_wconv(const float* __restrict__ qkvw, const float* __restrict__ o1w,
             const float* __restrict__ o2w, _Float16* __restrict__ kvw,
             _Float16* __restrict__ qw, _Float16* __restrict__ o1h,
             _Float16* __restrict__ o2h) {
  int t = blockIdx.x * 256 + threadIdx.x;        // 0..81919
  if (t < 32768) {
    int r = t >> 7, c = t & 127;
    int h = r >> 5, rr = r & 31;
    int src = h * 48 + 16 + rr;
    int mb  = h * 48 + 16 + (rr & 16);           // base row of this k- or v-block
    float s = 0.0f;
#pragma unroll
    for (int d = 0; d < 16; d++) s += qkvw[(mb + d) * 128 + c];
    kvw[t] = (_Float16)(qkvw[src * 128 + c] - 0.0625f * s);
  } else if (t < 49152) {
    int i = t - 32768;
    int r = i >> 7, c = i & 127;
    int src = (r >> 4) * 48 + (r & 15);
    qw[i] = (_Float16)qkvw[src * 128 + c];
  } else if (t < 65536) {
    int i = t - 49152;
    o1h[i] = (_Float16)o1w[i];
  } else {
    int i = t - 65536;
    o2h[i] = (_Float16)o2w[i];
  }
}

// ---------------- kernel A: k,v GEMM + LayerNorm + kv outer-product partials --
// Grid 2048 = 8 b * 256 cb; each block: 4 chunks of 64 px. Wave w owns heads 2w,2w+1.
// (256,3): unified budget 170; usage ~148 (84 arch + 64 acc) -> no spill.
// NO register prefetch (round 3's ld[8] pushed unified regs to ~180 -> spill).
// Ping-pong LDS: one barrier per chunk.
__global__ __launch_bounds__(256, 3)
void k_qkv_kv(const float* __restrict__ x, const _Float16* __restrict__ kvw,
              const float* __restrict__ klw, const float* __restrict__ klb,
              const float* __restrict__ vlw, const float* __restrict__ vlb,
              float* __restrict__ partial) {
  __shared__ _Float16 xs[2][8192];               // 2 x 64px x 128ch, swizzled
  const int t = threadIdx.x;
  const int lane = t & 63, w = t >> 6;
  const int quad = lane >> 4, l16 = lane & 15;
  const int b = blockIdx.x >> 8, cb = blockIdx.x & 255;
  const float* xb = x + (long)b * 8388608;       // b*128*65536
  const int cbase = t >> 4, p0 = 4 * (t & 15);

  float kw0[2], kb0[2], vw0[2], vb0[2];
#pragma unroll
  for (int hh = 0; hh < 2; hh++) {
    int h = 2 * w + hh;
    kw0[hh] = klw[h * 16 + l16]; kb0[hh] = klb[h * 16 + l16];
    vw0[hh] = vlw[h * 16 + l16]; vb0[hh] = vlb[h * 16 + l16];
  }

  float4_t kvacc[2] = {};                        // kv accumulator, C-layout

  for (int ch = 0; ch < 4; ch++) {
    _Float16* bs = xs[ch & 1];
    const int n0 = cb * 256 + ch * 64;
    // stage x tile -> LDS fp16, swizzled (transient regs only)
#pragma unroll
    for (int i = 0; i < 8; i++) {
      int c = i * 16 + cbase;
      float4 v = *(const float4*)(xb + ((long)c << 16) + n0 + p0);
      bs[(p0 + 0) * 128 + swz(p0 + 0, c)] = (_Float16)v.x;
      bs[(p0 + 1) * 128 + swz(p0 + 1, c)] = (_Float16)v.y;
      bs[(p0 + 2) * 128 + swz(p0 + 2, c)] = (_Float16)v.z;
      bs[(p0 + 3) * 128 + swz(p0 + 3, c)] = (_Float16)v.w;
    }
    __syncthreads();                             // single barrier per chunk

    // C[p][och] = X[p][c] * Wkv[och][c]; wave och slice = [64w, 64w+64)
    float4_t acc[4][4] = {};                     // [m-tile][o-tile]
#pragma unroll
    for (int k = 0; k < 4; k++) {
      half8_t A[4];
#pragma unroll
      for (int mt = 0; mt < 4; mt++) {
        int row = mt * 16 + l16;
        A[mt] = *(const half8_t*)(bs + row * 128 + swz8(row, k * 4 + quad));
      }
#pragma unroll
      for (int ot = 0; ot < 4; ot++) {
        half8_t Bf = *(const half8_t*)(kvw + (w * 64 + ot * 16 + l16) * 128 + k * 32 + quad * 8);
#pragma unroll
        for (int mt = 0; mt < 4; mt++)
          acc[mt][ot] = __builtin_amdgcn_mfma_f32_16x16x32_f16(A[mt], Bf, acc[mt][ot], 0, 0, 0);
      }
    }

    // LN(k), LN(v): mean pre-folded into kvw -> std = sqrt(sum(k'^2)/15),
    // inv = rcp(std + EPS).  Then kv += K^T V via 16x16x16 MFMA.
#pragma unroll
    for (int hh = 0; hh < 2; hh++) {
#pragma unroll
      for (int mt = 0; mt < 4; mt++) {
        half4_t kf, vf;
#pragma unroll
        for (int rr = 0; rr < 4; rr++) {
          float kx = acc[mt][2 * hh + 0][rr];
          float vx = acc[mt][2 * hh + 1][rr];
          float s2k = rsum16(kx * kx);
          float s2v = rsum16(vx * vx);
          float rk = __builtin_amdgcn_rcpf(
              __builtin_fmaf(__builtin_amdgcn_sqrtf(s2k), 0.25819889f, EPS));
          float rv = __builtin_amdgcn_rcpf(
              __builtin_fmaf(__builtin_amdgcn_sqrtf(s2v), 0.25819889f, EPS));
          kf[rr] = (_Float16)((kw0[hh] * rk) * kx + kb0[hh]);
          vf[rr] = (_Float16)((vw0[hh] * rv) * vx + vb0[hh]);
        }
        kvacc[hh] = __builtin_amdgcn_mfma_f32_16x16x16f16(kf, vf, kvacc[hh], 0, 0, 0);
      }
    }
    // no trailing barrier: next chunk writes the OTHER buffer; the top-of-loop
    // barrier (after iter ch) separates this chunk's reads from iter ch+2's writes.
  }

  // write per-block partial kv: [block][h][d][e]
#pragma unroll
  for (int hh = 0; hh < 2; hh++) {
    int h = 2 * w + hh;
#pragma unroll
    for (int rr = 0; rr < 4; rr++) {
      int d = quad * 4 + rr;
      partial[((long)blockIdx.x * 8 + h) * 256 + d * 16 + l16] = kvacc[hh][rr];
    }
  }
}

// ------- reducer: sum partials, /N, then fold q-weight: wob = kv^T @ qw ------
// Block bh = b*8+h.  o = (x Wq^T) kv = x (kv^T Wq)^T, so build per-batch
// combined weight wob[b][h*16+e][c] = sum_d kv[d][e] * qw[h*16+d][c].
// Kernel C then needs NO q stage at all.
__global__ __launch_bounds__(256)
void k_reduce(const float* __restrict__ partial, const _Float16* __restrict__ qw,
              _Float16* __restrict__ wob) {
  __shared__ float kv[16][16];                   // kv[d][e], scaled by 1/N
  const int bh = blockIdx.x;                     // b*8+h
  const int t = threadIdx.x;                     // t = d*16+e
  const int b = bh >> 3, h = bh & 7;
  float s = 0.0f;
#pragma unroll 8
  for (int cb = 0; cb < 256; cb++)
    s += partial[((long)(b * 256 + cb) * 8 + h) * 256 + t];
  kv[t >> 4][t & 15] = s * (1.0f / 65536.0f);
  __syncthreads();

  const int e = t >> 4, c0 = (t & 15) * 8;       // thread -> (e, 8 cols)
  float accw[8] = {};
#pragma unroll
  for (int d = 0; d < 16; d++) {
    float kde = kv[d][e];
    half8_t qv = *(const half8_t*)(qw + (h * 16 + d) * 128 + c0);
#pragma unroll
    for (int j = 0; j < 8; j++) accw[j] = __builtin_fmaf(kde, (float)qv[j], accw[j]);
  }
  _Float16* dst = wob + b * 16384 + (h * 16 + e) * 128 + c0;
#pragma unroll
  for (int j = 0; j < 8; j++) dst[j] = (_Float16)accw[j];
}

// ---------------- shared GEMM helper: C[p][och], och slice [32w,32w+32) -------
// src is a swizzled [64][128] tile (row stride 128); wgt is row-major [128][128].
__device__ __forceinline__ void gemm_128(const _Float16* src, const _Float16* wgt,
                                         int w, int l16, int quad, float4_t (&acc)[4][2]) {
#pragma unroll
  for (int k = 0; k < 4; k++) {
    half8_t A[4];
#pragma unroll
    for (int mt = 0; mt < 4; mt++) {
      int row = mt * 16 + l16;
      A[mt] = *(const half8_t*)(src + row * 128 + swz8(row, k * 4 + quad));
    }
#pragma unroll
    for (int ot = 0; ot < 2; ot++) {
      half8_t Bf = *(const half8_t*)(wgt + (w * 32 + ot * 16 + l16) * 128 + k * 32 + quad * 8);
#pragma unroll
      for (int mt = 0; mt < 4; mt++)
        acc[mt][ot] = __builtin_amdgcn_mfma_f32_16x16x32_f16(A[mt], Bf, acc[mt][ot], 0, 0, 0);
    }
  }
}

// ------------- kernel C: o GEMM (+x) + o1/gelu + o2/gelu, 3 clean GEMMs ------
// (256,3): unified budget 170 (round 3's (256,4)=128 spilled 1.3GB to scratch).
// q stage eliminated via the wob fold; x residual read once at acc positions.
__global__ __launch_bounds__(256, 3)
void k_attn_out(const float* __restrict__ x, const _Float16* __restrict__ wob,
                const _Float16* __restrict__ o1h, const _Float16* __restrict__ o2h,
                float* __restrict__ out) {
  __shared__ _Float16 bufA[8192];                // x, later u (swizzled)
  __shared__ _Float16 bufB[8192];                // ret, later y (swizzled)
  const int t = threadIdx.x;
  const int lane = t & 63, w = t >> 6;
  const int quad = lane >> 4, l16 = lane & 15;
  const int b = blockIdx.x >> 10;
  const int n0 = (blockIdx.x & 1023) << 6;
  const float* xb = x + (long)b * 8388608;
  const int cbase = t >> 4, p0 = 4 * (t & 15);

#pragma unroll
  for (int i = 0; i < 8; i++) {
    int c = i * 16 + cbase;
    float4 v = *(const float4*)(xb + ((long)c << 16) + n0 + p0);
    bufA[(p0 + 0) * 128 + swz(p0 + 0, c)] = (_Float16)v.x;
    bufA[(p0 + 1) * 128 + swz(p0 + 1, c)] = (_Float16)v.y;
    bufA[(p0 + 2) * 128 + swz(p0 + 2, c)] = (_Float16)v.z;
    bufA[(p0 + 3) * 128 + swz(p0 + 3, c)] = (_Float16)v.w;
  }
  __syncthreads();

  // ret = x @ wob_b^T + x  -> bufB ; snapshot x residual for the y stage
  float4_t oa[4][2] = {};
  gemm_128(bufA, wob + b * 16384, w, l16, quad, oa);
  _Float16 xres[4][2][4];                        // static indexing -> registers
#pragma unroll
  for (int mt = 0; mt < 4; mt++)
#pragma unroll
    for (int ot = 0; ot < 2; ot++)
#pragma unroll
      for (int rr = 0; rr < 4; rr++) {
        int p = mt * 16 + quad * 4 + rr, c = w * 32 + ot * 16 + l16;
        _Float16 xv = bufA[p * 128 + swz(p, c)];
        xres[mt][ot][rr] = xv;
        bufB[p * 128 + swz(p, c)] = (_Float16)(oa[mt][ot][rr] + (float)xv);
      }
  __syncthreads();

  // u = gelu(ret @ o1^T) -> bufA (overwrites x; residual already snapshotted)
  float4_t ua[4][2] = {};
  gemm_128(bufB, o1h, w, l16, quad, ua);
#pragma unroll
  for (int mt = 0; mt < 4; mt++)
#pragma unroll
    for (int ot = 0; ot < 2; ot++)
#pragma unroll
      for (int rr = 0; rr < 4; rr++) {
        int p = mt * 16 + quad * 4 + rr, c = w * 32 + ot * 16 + l16;
        bufA[p * 128 + swz(p, c)] = (_Float16)gelu_f(ua[mt][ot][rr]);
      }
  __syncthreads();

  // y = gelu(u @ o2^T + x) -> bufB
  float4_t ya[4][2] = {};
  gemm_128(bufA, o2h, w, l16, quad, ya);
#pragma unroll
  for (int mt = 0; mt < 4; mt++)
#pragma unroll
    for (int ot = 0; ot < 2; ot++)
#pragma unroll
      for (int rr = 0; rr < 4; rr++) {
        int p = mt * 16 + quad * 4 + rr, c = w * 32 + ot * 16 + l16;
        bufB[p * 128 + swz(p, c)] = (_Float16)gelu_f(ya[mt][ot][rr] + (float)xres[mt][ot][rr]);
      }
  __syncthreads();

  // coalesced fp32 store via LDS transpose
#pragma unroll
  for (int i = 0; i < 8; i++) {
    int c = i * 16 + cbase;
    float4 o4;
    o4.x = (float)bufB[(p0 + 0) * 128 + swz(p0 + 0, c)];
    o4.y = (float)bufB[(p0 + 1) * 128 + swz(p0 + 1, c)];
    o4.z = (float)bufB[(p0 + 2) * 128 + swz(p0 + 2, c)];
    o4.w = (float)bufB[(p0 + 3) * 128 + swz(p0 + 3, c)];
    *(float4*)(out + ((long)b * 128 + c) * 65536 + n0 + p0) = o4;
  }
}

extern "C" void kernel_launch(void* const* d_in, const int* in_sizes, int n_in,
                              void* d_out, int out_size, void* d_ws, size_t ws_size,
                              hipStream_t stream) {
  const float* x    = (const float*)d_in[0];
  const float* qkvw = (const float*)d_in[1];
  const float* o1w  = (const float*)d_in[2];
  const float* o2w  = (const float*)d_in[3];
  const float* klw  = (const float*)d_in[4];
  const float* klb  = (const float*)d_in[5];
  const float* vlw  = (const float*)d_in[6];
  const float* vlb  = (const float*)d_in[7];
  float* out = (float*)d_out;
  char* ws = (char*)d_ws;
  _Float16* kvw  = (_Float16*)(ws + 0);        // 256x128 fp16    (64 KB)
  _Float16* qw   = (_Float16*)(ws + 65536);    // 128x128 fp16    (32 KB)
  _Float16* o1h  = (_Float16*)(ws + 98304);    // 128x128 fp16    (32 KB)
  _Float16* o2h  = (_Float16*)(ws + 131072);   // 128x128 fp16    (32 KB)
  _Float16* wob  = (_Float16*)(ws + 163840);   // 8x128x128 fp16  (256 KB)
  float* partial = (float*)(ws + 425984);      // 2048x8x256 fp32 (16 MB)

  k_wconv<<<320, 256, 0, stream>>>(qkvw, o1w, o2w, kvw, qw, o1h, o2h);
  k_qkv_kv<<<2048, 256, 0, stream>>>(x, kvw, klw, klb, vlw, vlb, partial);
  k_reduce<<<64, 256, 0, stream>>>(partial, qw, wob);
  k_attn_out<<<8192, 256, 0, stream>>>(x, wob, o1h, o2h, out);
}